// Round 4
// baseline (142.409 us; speedup 1.0000x reference)
//
#include <hip/hip_runtime.h>
#include <hip/hip_bf16.h>
#include <math.h>

#define S_LEN 2048
#define E_DIM 1024
#define NHEAD 8
#define DH 128
#define E3 3072

typedef short bf16x8 __attribute__((ext_vector_type(8)));
typedef short bf16x4 __attribute__((ext_vector_type(4)));
typedef float f32x4 __attribute__((ext_vector_type(4)));

#define MFMA32(a,b,c) __builtin_amdgcn_mfma_f32_16x16x32_bf16(a,b,c,0,0,0)

__device__ __forceinline__ unsigned short f2bf(float f){
  union{float f; unsigned u;} x; x.f = f;
  unsigned r = x.u + 0x7FFF + ((x.u>>16)&1);
  return (unsigned short)(r>>16);
}

__device__ __forceinline__ unsigned cvtpk(float lo, float hi){
  unsigned r;
  asm("v_cvt_pk_bf16_f32 %0, %1, %2" : "=v"(r) : "v"(lo), "v"(hi));
  return r;
}

__device__ __forceinline__ float logsigf(float x){
  return fminf(x, 0.f) - log1pf(expf(-fabsf(x)));
}

// ---------------- Kernel A: gates + q/k bf16 conversion (fused) ------------
__global__ __launch_bounds__(256) void gates_qk(
    const float* __restrict__ q, const float* __restrict__ k, const float* __restrict__ v,
    const float* __restrict__ igw, const float* __restrict__ igb,
    const float* __restrict__ fgw, const float* __restrict__ fgb,
    float* __restrict__ ig_out, float* __restrict__ lsf_out,
    ushort* __restrict__ qbo, ushort* __restrict__ kbo){
  const int t0 = blockIdx.x*4;
  const int tid = threadIdx.x;
  const int lane = tid & 63, wv = tid >> 6;
  float acc[64];
  #pragma unroll
  for (int a=0;a<64;++a) acc[a]=0.f;
  const float sc = 0.08838834764831845f;  // 1/sqrt(128)
  #pragma unroll
  for (int step=0; step<3; ++step){
    const float* src = (step==0)? q : ((step==1)? k : v);
    float4 in4[4];
    #pragma unroll
    for (int r=0;r<4;++r) in4[r] = ((const float4*)src)[(size_t)(t0+r)*256 + tid];
    if (step==0){
      #pragma unroll
      for (int r=0;r<4;++r){
        ushort4 o; o.x=f2bf(in4[r].x*sc); o.y=f2bf(in4[r].y*sc);
        o.z=f2bf(in4[r].z*sc); o.w=f2bf(in4[r].w*sc);
        ((ushort4*)qbo)[(size_t)(t0+r)*256 + tid] = o;
      }
    } else if (step==1){
      #pragma unroll
      for (int r=0;r<4;++r){
        ushort4 o; o.x=f2bf(in4[r].x); o.y=f2bf(in4[r].y);
        o.z=f2bf(in4[r].z); o.w=f2bf(in4[r].w);
        ((ushort4*)kbo)[(size_t)(t0+r)*256 + tid] = o;
      }
    }
    const int wj = step*256 + tid;   // float4 index, row stride E3/4=768
    #pragma unroll
    for (int o=0;o<8;++o){
      float4 wI = ((const float4*)igw)[o*768 + wj];
      float4 wF = ((const float4*)fgw)[o*768 + wj];
      #pragma unroll
      for (int r=0;r<4;++r){
        acc[o*4+r]    = fmaf(in4[r].x, wI.x, acc[o*4+r]);
        acc[o*4+r]    = fmaf(in4[r].y, wI.y, acc[o*4+r]);
        acc[o*4+r]    = fmaf(in4[r].z, wI.z, acc[o*4+r]);
        acc[o*4+r]    = fmaf(in4[r].w, wI.w, acc[o*4+r]);
        acc[32+o*4+r] = fmaf(in4[r].x, wF.x, acc[32+o*4+r]);
        acc[32+o*4+r] = fmaf(in4[r].y, wF.y, acc[32+o*4+r]);
        acc[32+o*4+r] = fmaf(in4[r].z, wF.z, acc[32+o*4+r]);
        acc[32+o*4+r] = fmaf(in4[r].w, wF.w, acc[32+o*4+r]);
      }
    }
  }
  // butterfly: lane l ends with wave-total of acc[bitrev6(l)]
  int cnt = 32;
  #pragma unroll
  for (int s=0; s<6; ++s){
    const bool hi = (lane >> s) & 1;
    #pragma unroll
    for (int a=0; a<32; ++a){
      if (a < cnt){
        float sent = hi ? acc[a] : acc[a+cnt];
        float got = __shfl_xor(sent, 1<<s, 64);
        acc[a] = (hi ? acc[a+cnt] : acc[a]) + got;
      }
    }
    cnt >>= 1;
  }
  __shared__ float red[4][64];
  red[wv][lane] = acc[0];
  __syncthreads();
  if (tid < 64){
    float tot = red[0][tid]+red[1][tid]+red[2][tid]+red[3][tid];
    int a = (int)(__brev((unsigned)tid) >> 26);   // bitrev6
    int f = a >> 5, o = (a>>2)&7, r = a&3;
    int t = t0 + r;
    if (f==0) ig_out[o*S_LEN + t] = tot + igb[o];
    else      lsf_out[o*S_LEN + t] = logsigf(tot + fgb[o]);
  }
}

// ---------------- Kernel B: per-head scans ---------------------------------
__global__ __launch_bounds__(256) void scan_kernel(
    const float* __restrict__ ig, const float* __restrict__ lsf,
    float* __restrict__ cs_out, float* __restrict__ M_out, float* __restrict__ m_out){
  const int h = blockIdx.x;
  const int tid = threadIdx.x;
  __shared__ float tt[256];
  const int base = tid*8;
  const float* src = lsf + h*S_LEN;
  float loc[8]; float tot = 0.f;
  #pragma unroll
  for (int i=0;i<8;++i){ tot += src[base+i]; loc[i]=tot; }
  tt[tid]=tot; __syncthreads();
  for (int off=1; off<256; off<<=1){
    float add = (tid>=off)? tt[tid-off] : 0.f;
    __syncthreads();
    tt[tid] += add;
    __syncthreads();
  }
  const float excl = tt[tid] - tot;
  float csv[8];
  #pragma unroll
  for (int i=0;i<8;++i){ csv[i] = excl + loc[i]; cs_out[h*S_LEN+base+i]=csv[i]; }
  const float* igp = ig + h*S_LEN;
  float mloc[8], mval[8]; float mtot = -INFINITY;
  #pragma unroll
  for (int i=0;i<8;++i){
    float m = igp[base+i] - csv[i];
    mval[i] = m;
    mtot = fmaxf(mtot, m);
    mloc[i] = mtot;
  }
  __syncthreads();
  tt[tid]=mtot; __syncthreads();
  for (int off=1; off<256; off<<=1){
    float add = (tid>=off)? tt[tid-off] : -INFINITY;
    __syncthreads();
    tt[tid] = fmaxf(tt[tid], add);
    __syncthreads();
  }
  const float exclm = (tid>0)? tt[tid-1] : -INFINITY;
  #pragma unroll
  for (int i=0;i<8;++i){
    M_out[h*S_LEN+base+i] = fmaxf(exclm, mloc[i]);
    m_out[h*S_LEN+base+i] = mval[i];
  }
}

// ---------------- Kernel P2: V transpose -> vt[h][d][s] bf16 ---------------
__global__ __launch_bounds__(256) void vtrans(
    const float* __restrict__ v, ushort* __restrict__ vt){
  const int s0 = blockIdx.x*64, d0 = blockIdx.y*64, h = blockIdx.z;
  __shared__ float T[64][65];
  const int r = threadIdx.x>>2, cq = threadIdx.x&3;
  #pragma unroll
  for (int i=0;i<4;++i){
    int col = cq*16 + i*4;
    float4 val = *(const float4*)(v + (size_t)(s0+r)*E_DIM + h*DH + d0 + col);
    T[r][col]=val.x; T[r][col+1]=val.y; T[r][col+2]=val.z; T[r][col+3]=val.w;
  }
  __syncthreads();
  ushort tmp[16];
  #pragma unroll
  for (int i=0;i<16;++i) tmp[i] = f2bf(T[cq*16+i][r]);
  ushort* dst = vt + ((size_t)(h*DH + d0 + r))*S_LEN + s0 + cq*16;
  uint4 o0, o1;
  ushort* p0 = (ushort*)&o0; ushort* p1 = (ushort*)&o1;
  #pragma unroll
  for (int i=0;i<8;++i){ p0[i]=tmp[i]; p1[i]=tmp[8+i]; }
  *(uint4*)dst = o0;
  *(uint4*)(dst+8) = o1;
}

// ---------------- Kernel C: barrier-free swapped-QK MFMA main --------------
// Block (h,p): passes qt=p then 63-p. 8 waves = (qh,sq). Per 128-s PAIR of
// 64-s units: QK^T-swapped (8 MFMA32) -> P in regs -> pack pair into one
// K=32 PV fragment (8 MFMA32). Only mfma_f32_16x16x32_bf16 used.
#define LOADP(jj, S) {                                                   \
    const ushort* kp0_ = kA + (size_t)(2*(jj))*64*E_DIM;                 \
    const ushort* kp1_ = kp0_ + (size_t)64*E_DIM;                        \
    ka##S##00 = *(const bf16x8*)(kp0_);                                  \
    ka##S##01 = *(const bf16x8*)(kp0_+32);                               \
    ka##S##02 = *(const bf16x8*)(kp0_+64);                               \
    ka##S##03 = *(const bf16x8*)(kp0_+96);                               \
    ka##S##10 = *(const bf16x8*)(kp1_);                                  \
    ka##S##11 = *(const bf16x8*)(kp1_+32);                               \
    ka##S##12 = *(const bf16x8*)(kp1_+64);                               \
    ka##S##13 = *(const bf16x8*)(kp1_+96);                               \
    const ushort* vp0_ = vB + (2*(jj))*64;                               \
    m4##S##0 = *(const f32x4*)(mP + (2*(jj))*64);                        \
    m4##S##1 = *(const f32x4*)(mP + (2*(jj))*64 + 64);                   \
    bf16x4 lo_, hi_;                                                     \
    lo_ = *(const bf16x4*)(vp0_ + 0*16*S_LEN);                           \
    hi_ = *(const bf16x4*)(vp0_ + 0*16*S_LEN + 64);                      \
    vb##S##0 = __builtin_shufflevector(lo_, hi_, 0,1,2,3,4,5,6,7);       \
    lo_ = *(const bf16x4*)(vp0_ + 1*16*S_LEN);                           \
    hi_ = *(const bf16x4*)(vp0_ + 1*16*S_LEN + 64);                      \
    vb##S##1 = __builtin_shufflevector(lo_, hi_, 0,1,2,3,4,5,6,7);       \
    lo_ = *(const bf16x4*)(vp0_ + 2*16*S_LEN);                           \
    hi_ = *(const bf16x4*)(vp0_ + 2*16*S_LEN + 64);                      \
    vb##S##2 = __builtin_shufflevector(lo_, hi_, 0,1,2,3,4,5,6,7);       \
    lo_ = *(const bf16x4*)(vp0_ + 3*16*S_LEN);                           \
    hi_ = *(const bf16x4*)(vp0_ + 3*16*S_LEN + 64);                      \
    vb##S##3 = __builtin_shufflevector(lo_, hi_, 0,1,2,3,4,5,6,7);       \
    lo_ = *(const bf16x4*)(vp0_ + 4*16*S_LEN);                           \
    hi_ = *(const bf16x4*)(vp0_ + 4*16*S_LEN + 64);                      \
    vb##S##4 = __builtin_shufflevector(lo_, hi_, 0,1,2,3,4,5,6,7);       \
    lo_ = *(const bf16x4*)(vp0_ + 5*16*S_LEN);                           \
    hi_ = *(const bf16x4*)(vp0_ + 5*16*S_LEN + 64);                      \
    vb##S##5 = __builtin_shufflevector(lo_, hi_, 0,1,2,3,4,5,6,7);       \
    lo_ = *(const bf16x4*)(vp0_ + 6*16*S_LEN);                           \
    hi_ = *(const bf16x4*)(vp0_ + 6*16*S_LEN + 64);                      \
    vb##S##6 = __builtin_shufflevector(lo_, hi_, 0,1,2,3,4,5,6,7);       \
    lo_ = *(const bf16x4*)(vp0_ + 7*16*S_LEN);                           \
    hi_ = *(const bf16x4*)(vp0_ + 7*16*S_LEN + 64);                      \
    vb##S##7 = __builtin_shufflevector(lo_, hi_, 0,1,2,3,4,5,6,7); }

#define COMPP(jj, S) {                                                   \
    f32x4 c0={0.f,0.f,0.f,0.f}, c1=c0, c2=c0, c3=c0;                     \
    c0 = MFMA32(ka##S##00, qf0, c0);                                     \
    c1 = MFMA32(ka##S##01, qf1, c1);                                     \
    c0 = MFMA32(ka##S##02, qf2, c0);                                     \
    c1 = MFMA32(ka##S##03, qf3, c1);                                     \
    c2 = MFMA32(ka##S##10, qf0, c2);                                     \
    c3 = MFMA32(ka##S##11, qf1, c3);                                     \
    c2 = MFMA32(ka##S##12, qf2, c2);                                     \
    c3 = MFMA32(ka##S##13, qf3, c3);                                     \
    const int sb0_ = (2*(jj))*64 + sq*16 + g*4;                          \
    float pw[8];                                                         \
    _Pragma("unroll")                                                    \
    for (int r_=0;r_<4;++r_){                                            \
      float sv_ = c0[r_]+c1[r_];                                         \
      float ex_ = __expf(m4##S##0[r_]-Mq);                               \
      pw[r_] = (sb0_+r_ <= tg) ? sv_*ex_ : 0.f;                          \
      float sv2_ = c2[r_]+c3[r_];                                        \
      float ex2_ = __expf(m4##S##1[r_]-Mq);                              \
      pw[4+r_] = (sb0_+64+r_ <= tg) ? sv2_*ex2_ : 0.f;                   \
    }                                                                    \
    rsq += pw[0]+pw[1]+pw[2]+pw[3]+pw[4]+pw[5]+pw[6]+pw[7];              \
    bf16x8 pa_; unsigned* pau_ = (unsigned*)&pa_;                        \
    pau_[0]=cvtpk(pw[0],pw[1]); pau_[1]=cvtpk(pw[2],pw[3]);              \
    pau_[2]=cvtpk(pw[4],pw[5]); pau_[3]=cvtpk(pw[6],pw[7]);              \
    o0 = MFMA32(pa_, vb##S##0, o0);                                      \
    o1 = MFMA32(pa_, vb##S##1, o1);                                      \
    o2 = MFMA32(pa_, vb##S##2, o2);                                      \
    o3 = MFMA32(pa_, vb##S##3, o3);                                      \
    o4 = MFMA32(pa_, vb##S##4, o4);                                      \
    o5 = MFMA32(pa_, vb##S##5, o5);                                      \
    o6 = MFMA32(pa_, vb##S##6, o6);                                      \
    o7 = MFMA32(pa_, vb##S##7, o7); }

__global__ __launch_bounds__(512) void mlstm_mfma2(
    const ushort* __restrict__ qb, const ushort* __restrict__ kb,
    const ushort* __restrict__ vt,
    const float* __restrict__ csb, const float* __restrict__ Mxb,
    const float* __restrict__ mbb,
    const float* __restrict__ nw, float* __restrict__ out){
  const int h = blockIdx.x, p = blockIdx.y;
  const int tid = threadIdx.x, l = tid & 63, w = tid >> 6;
  const int qh = w >> 2, sq = w & 3;
  const int g = l >> 4, m16 = l & 15;

  __shared__ float Osum[2][4][16][132];
  __shared__ float rsL[2][4][16];
  __shared__ float LNp[2][4][16][2];

  const ushort* kbh = kb + h*DH;
  const ushort* vth = vt + (size_t)h*DH*S_LEN;
  const float* mh = mbb + h*S_LEN;

  for (int pass=0; pass<2; ++pass){
    const int qt = pass ? (63 - p) : p;
    const int t0 = qt*32;
    const int tg = t0 + qh*16 + m16;         // this lane's q (QK C-col)
    const float Mq = Mxb[h*S_LEN + tg];
    const int nkb = (qt>>1) + 1;
    const int npair = (nkb+1) >> 1;

    bf16x8 qf0,qf1,qf2,qf3;
    { const ushort* qsrc = qb + (size_t)tg*E_DIM + h*DH + g*8;
      qf0 = *(const bf16x8*)(qsrc);
      qf1 = *(const bf16x8*)(qsrc+32);
      qf2 = *(const bf16x8*)(qsrc+64);
      qf3 = *(const bf16x8*)(qsrc+96); }

    const ushort* kA = kbh + (size_t)(sq*16 + m16)*E_DIM + g*8;
    const ushort* vB = vth + (size_t)m16*S_LEN + sq*16 + g*4;
    const float*  mP = mh + sq*16 + g*4;

    f32x4 o0={0.f,0.f,0.f,0.f},o1=o0,o2=o0,o3=o0,o4=o0,o5=o0,o6=o0,o7=o0;
    float rsq = 0.f;

    bf16x8 kaA00,kaA01,kaA02,kaA03, kaA10,kaA11,kaA12,kaA13;
    bf16x8 kaB00,kaB01,kaB02,kaB03, kaB10,kaB11,kaB12,kaB13;
    bf16x8 vbA0,vbA1,vbA2,vbA3,vbA4,vbA5,vbA6,vbA7;
    bf16x8 vbB0,vbB1,vbB2,vbB3,vbB4,vbB5,vbB6,vbB7;
    f32x4 m4A0, m4A1, m4B0, m4B1;

    LOADP(0, A);
    int j = 0;
    while (true){
      if (j+1 < npair) LOADP(j+1, B);
      COMPP(j, A);
      ++j; if (j == npair) break;
      if (j+1 < npair) LOADP(j+1, A);
      COMPP(j, B);
      ++j; if (j == npair) break;
    }

    // -------- epilogue: cross-sq reduction + normalizer + LN --------
    __syncthreads();   // previous pass's LDS readers done
    #pragma unroll
    for (int r=0;r<4;++r){
      Osum[qh][sq][g*4+r][0*16+m16] = o0[r];
      Osum[qh][sq][g*4+r][1*16+m16] = o1[r];
      Osum[qh][sq][g*4+r][2*16+m16] = o2[r];
      Osum[qh][sq][g*4+r][3*16+m16] = o3[r];
      Osum[qh][sq][g*4+r][4*16+m16] = o4[r];
      Osum[qh][sq][g*4+r][5*16+m16] = o5[r];
      Osum[qh][sq][g*4+r][6*16+m16] = o6[r];
      Osum[qh][sq][g*4+r][7*16+m16] = o7[r];
    }
    rsq += __shfl_xor(rsq, 16, 64);
    rsq += __shfl_xor(rsq, 32, 64);
    if (l < 16) rsL[qh][sq][m16] = rsq;
    __syncthreads();

    const int db = sq;
    const int d4 = db*32 + (l&7)*4;
    f32x4 hv0, hv1;
    #pragma unroll
    for (int qp=0; qp<2; ++qp){
      const int qr = (l>>3) + qp*8;
      f32x4 os = {0.f,0.f,0.f,0.f};
      #pragma unroll
      for (int s4=0;s4<4;++s4){
        f32x4 part = *(const f32x4*)&Osum[qh][s4][qr][d4];
        os[0]+=part[0]; os[1]+=part[1]; os[2]+=part[2]; os[3]+=part[3];
      }
      float rstot = rsL[qh][0][qr]+rsL[qh][1][qr]+rsL[qh][2][qr]+rsL[qh][3][qr];
      const int tq = t0 + qh*16 + qr;
      float en = __expf(-(csb[h*S_LEN+tq] + Mxb[h*S_LEN+tq]));
      float iv = 1.f/(fmaxf(fabsf(rstot), en) + 1e-6f);
      f32x4 hvv;
      hvv[0]=os[0]*iv; hvv[1]=os[1]*iv; hvv[2]=os[2]*iv; hvv[3]=os[3]*iv;
      float s1 = hvv[0]+hvv[1]+hvv[2]+hvv[3];
      float s2 = hvv[0]*hvv[0]+hvv[1]*hvv[1]+hvv[2]*hvv[2]+hvv[3]*hvv[3];
      s1 += __shfl_xor(s1, 1, 64); s2 += __shfl_xor(s2, 1, 64);
      s1 += __shfl_xor(s1, 2, 64); s2 += __shfl_xor(s2, 2, 64);
      s1 += __shfl_xor(s1, 4, 64); s2 += __shfl_xor(s2, 4, 64);
      if ((l&7)==0){ LNp[qh][db][qr][0]=s1; LNp[qh][db][qr][1]=s2; }
      if (qp==0) hv0 = hvv; else hv1 = hvv;
    }
    __syncthreads();
    #pragma unroll
    for (int qp=0; qp<2; ++qp){
      const int qr = (l>>3) + qp*8;
      float s1t = LNp[qh][0][qr][0]+LNp[qh][1][qr][0]+LNp[qh][2][qr][0]+LNp[qh][3][qr][0];
      float s2t = LNp[qh][0][qr][1]+LNp[qh][1][qr][1]+LNp[qh][2][qr][1]+LNp[qh][3][qr][1];
      float mean = s1t * (1.f/128.f);
      float var  = s2t * (1.f/128.f) - mean*mean;
      float rstd = rsqrtf(var + 1e-5f);
      f32x4 hvv = qp==0 ? hv0 : hv1;
      f32x4 nwv = *(const f32x4*)(nw + h*DH + d4);
      f32x4 ov;
      ov[0]=(hvv[0]-mean)*rstd*nwv[0];
      ov[1]=(hvv[1]-mean)*rstd*nwv[1];
      ov[2]=(hvv[2]-mean)*rstd*nwv[2];
      ov[3]=(hvv[3]-mean)*rstd*nwv[3];
      *(f32x4*)(out + (size_t)(t0+qh*16+qr)*E_DIM + h*DH + d4) = ov;
    }
  }
}

extern "C" void kernel_launch(void* const* d_in, const int* in_sizes, int n_in,
                              void* d_out, int out_size, void* d_ws, size_t ws_size,
                              hipStream_t stream) {
  const float* q   = (const float*)d_in[0];
  const float* k   = (const float*)d_in[1];
  const float* v   = (const float*)d_in[2];
  const float* igw = (const float*)d_in[3];
  const float* igb = (const float*)d_in[4];
  const float* fgw = (const float*)d_in[5];
  const float* fgb = (const float*)d_in[6];
  const float* nw  = (const float*)d_in[7];
  float* outp = (float*)d_out;

  float* ws  = (float*)d_ws;
  float* ig  = ws;                 // NH*S
  float* lsf = ws + 1*NHEAD*S_LEN;
  float* csb = ws + 2*NHEAD*S_LEN;
  float* Mb  = ws + 3*NHEAD*S_LEN;
  float* mbf = ws + 4*NHEAD*S_LEN;
  ushort* qbb = (ushort*)(ws + 5*NHEAD*S_LEN);          // S*E bf16 (scaled)
  ushort* kbb = qbb + (size_t)S_LEN*E_DIM;              // S*E bf16
  ushort* vtb = kbb + (size_t)S_LEN*E_DIM;              // E*S bf16 (per-head V^T)

  gates_qk<<<512, 256, 0, stream>>>(q, k, v, igw, igb, fgw, fgb, ig, lsf, qbb, kbb);
  scan_kernel<<<NHEAD, 256, 0, stream>>>(ig, lsf, csb, Mb, mbf);
  vtrans<<<dim3(S_LEN/64, DH/64, NHEAD), 256, 0, stream>>>(v, vtb);
  mlstm_mfma2<<<dim3(NHEAD, 32), 512, 0, stream>>>(qbb, kbb, vtb, csb, Mb, mbf, nw, outp);
}

// Round 5
// 112.434 us; speedup vs baseline: 1.2666x; 1.2666x over previous
//
#include <hip/hip_runtime.h>
#include <hip/hip_bf16.h>
#include <math.h>

#define S_LEN 2048
#define E_DIM 1024
#define NHEAD 8
#define DH 128
#define E3 3072

typedef short bf16x8 __attribute__((ext_vector_type(8)));
typedef short bf16x4 __attribute__((ext_vector_type(4)));
typedef float f32x4 __attribute__((ext_vector_type(4)));

#define MFMA32(a,b,c) __builtin_amdgcn_mfma_f32_16x16x32_bf16(a,b,c,0,0,0)

__device__ __forceinline__ unsigned short f2bf(float f){
  union{float f; unsigned u;} x; x.f = f;
  unsigned r = x.u + 0x7FFF + ((x.u>>16)&1);
  return (unsigned short)(r>>16);
}

__device__ __forceinline__ unsigned cvtpk(float lo, float hi){
  unsigned r;
  asm("v_cvt_pk_bf16_f32 %0, %1, %2" : "=v"(r) : "v"(lo), "v"(hi));
  return r;
}

__device__ __forceinline__ float logsigf(float x){
  return fminf(x, 0.f) - log1pf(expf(-fabsf(x)));
}

typedef const __attribute__((address_space(1))) unsigned int* gas1_t;
typedef __attribute__((address_space(3))) unsigned int* las3_t;
__device__ __forceinline__ void stage16(const ushort* g, ushort* l){
  __builtin_amdgcn_global_load_lds((gas1_t)(const void*)g, (las3_t)(void*)l, 16, 0, 0);
}

// ---------------- Kernel A: gates + q/k bf16 conversion (fused) ------------
__global__ __launch_bounds__(256) void gates_qk(
    const float* __restrict__ q, const float* __restrict__ k, const float* __restrict__ v,
    const float* __restrict__ igw, const float* __restrict__ igb,
    const float* __restrict__ fgw, const float* __restrict__ fgb,
    float* __restrict__ ig_out, float* __restrict__ lsf_out,
    ushort* __restrict__ qbo, ushort* __restrict__ kbo){
  const int t0 = blockIdx.x*4;
  const int tid = threadIdx.x;
  const int lane = tid & 63, wv = tid >> 6;
  float acc[64];
  #pragma unroll
  for (int a=0;a<64;++a) acc[a]=0.f;
  const float sc = 0.08838834764831845f;  // 1/sqrt(128)
  #pragma unroll
  for (int step=0; step<3; ++step){
    const float* src = (step==0)? q : ((step==1)? k : v);
    float4 in4[4];
    #pragma unroll
    for (int r=0;r<4;++r) in4[r] = ((const float4*)src)[(size_t)(t0+r)*256 + tid];
    if (step==0){
      #pragma unroll
      for (int r=0;r<4;++r){
        ushort4 o; o.x=f2bf(in4[r].x*sc); o.y=f2bf(in4[r].y*sc);
        o.z=f2bf(in4[r].z*sc); o.w=f2bf(in4[r].w*sc);
        ((ushort4*)qbo)[(size_t)(t0+r)*256 + tid] = o;
      }
    } else if (step==1){
      #pragma unroll
      for (int r=0;r<4;++r){
        ushort4 o; o.x=f2bf(in4[r].x); o.y=f2bf(in4[r].y);
        o.z=f2bf(in4[r].z); o.w=f2bf(in4[r].w);
        ((ushort4*)kbo)[(size_t)(t0+r)*256 + tid] = o;
      }
    }
    const int wj = step*256 + tid;   // float4 index, row stride E3/4=768
    #pragma unroll
    for (int o=0;o<8;++o){
      float4 wI = ((const float4*)igw)[o*768 + wj];
      float4 wF = ((const float4*)fgw)[o*768 + wj];
      #pragma unroll
      for (int r=0;r<4;++r){
        acc[o*4+r]    = fmaf(in4[r].x, wI.x, acc[o*4+r]);
        acc[o*4+r]    = fmaf(in4[r].y, wI.y, acc[o*4+r]);
        acc[o*4+r]    = fmaf(in4[r].z, wI.z, acc[o*4+r]);
        acc[o*4+r]    = fmaf(in4[r].w, wI.w, acc[o*4+r]);
        acc[32+o*4+r] = fmaf(in4[r].x, wF.x, acc[32+o*4+r]);
        acc[32+o*4+r] = fmaf(in4[r].y, wF.y, acc[32+o*4+r]);
        acc[32+o*4+r] = fmaf(in4[r].z, wF.z, acc[32+o*4+r]);
        acc[32+o*4+r] = fmaf(in4[r].w, wF.w, acc[32+o*4+r]);
      }
    }
  }
  int cnt = 32;
  #pragma unroll
  for (int s=0; s<6; ++s){
    const bool hi = (lane >> s) & 1;
    #pragma unroll
    for (int a=0; a<32; ++a){
      if (a < cnt){
        float sent = hi ? acc[a] : acc[a+cnt];
        float got = __shfl_xor(sent, 1<<s, 64);
        acc[a] = (hi ? acc[a+cnt] : acc[a]) + got;
      }
    }
    cnt >>= 1;
  }
  __shared__ float red[4][64];
  red[wv][lane] = acc[0];
  __syncthreads();
  if (tid < 64){
    float tot = red[0][tid]+red[1][tid]+red[2][tid]+red[3][tid];
    int a = (int)(__brev((unsigned)tid) >> 26);   // bitrev6
    int f = a >> 5, o = (a>>2)&7, r = a&3;
    int t = t0 + r;
    if (f==0) ig_out[o*S_LEN + t] = tot + igb[o];
    else      lsf_out[o*S_LEN + t] = logsigf(tot + fgb[o]);
  }
}

// ---------------- Kernel B: per-head scans ---------------------------------
__global__ __launch_bounds__(256) void scan_kernel(
    const float* __restrict__ ig, const float* __restrict__ lsf,
    float* __restrict__ cs_out, float* __restrict__ M_out, float* __restrict__ m_out){
  const int h = blockIdx.x;
  const int tid = threadIdx.x;
  __shared__ float tt[256];
  const int base = tid*8;
  const float* src = lsf + h*S_LEN;
  float loc[8]; float tot = 0.f;
  #pragma unroll
  for (int i=0;i<8;++i){ tot += src[base+i]; loc[i]=tot; }
  tt[tid]=tot; __syncthreads();
  for (int off=1; off<256; off<<=1){
    float add = (tid>=off)? tt[tid-off] : 0.f;
    __syncthreads();
    tt[tid] += add;
    __syncthreads();
  }
  const float excl = tt[tid] - tot;
  float csv[8];
  #pragma unroll
  for (int i=0;i<8;++i){ csv[i] = excl + loc[i]; cs_out[h*S_LEN+base+i]=csv[i]; }
  const float* igp = ig + h*S_LEN;
  float mloc[8], mval[8]; float mtot = -INFINITY;
  #pragma unroll
  for (int i=0;i<8;++i){
    float m = igp[base+i] - csv[i];
    mval[i] = m;
    mtot = fmaxf(mtot, m);
    mloc[i] = mtot;
  }
  __syncthreads();
  tt[tid]=mtot; __syncthreads();
  for (int off=1; off<256; off<<=1){
    float add = (tid>=off)? tt[tid-off] : -INFINITY;
    __syncthreads();
    tt[tid] = fmaxf(tt[tid], add);
    __syncthreads();
  }
  const float exclm = (tid>0)? tt[tid-1] : -INFINITY;
  #pragma unroll
  for (int i=0;i<8;++i){
    M_out[h*S_LEN+base+i] = fmaxf(exclm, mloc[i]);
    m_out[h*S_LEN+base+i] = mval[i];
  }
}

// ---------------- Kernel P2: V transpose -> vt[h][d][s] bf16 ---------------
__global__ __launch_bounds__(256) void vtrans(
    const float* __restrict__ v, ushort* __restrict__ vt){
  const int s0 = blockIdx.x*64, d0 = blockIdx.y*64, h = blockIdx.z;
  __shared__ float T[64][65];
  const int r = threadIdx.x>>2, cq = threadIdx.x&3;
  #pragma unroll
  for (int i=0;i<4;++i){
    int col = cq*16 + i*4;
    float4 val = *(const float4*)(v + (size_t)(s0+r)*E_DIM + h*DH + d0 + col);
    T[r][col]=val.x; T[r][col+1]=val.y; T[r][col+2]=val.z; T[r][col+3]=val.w;
  }
  __syncthreads();
  ushort tmp[16];
  #pragma unroll
  for (int i=0;i<16;++i) tmp[i] = f2bf(T[cq*16+i][r]);
  ushort* dst = vt + ((size_t)(h*DH + d0 + r))*S_LEN + s0 + cq*16;
  uint4 o0, o1;
  ushort* p0 = (ushort*)&o0; ushort* p1 = (ushort*)&o1;
  #pragma unroll
  for (int i=0;i<8;++i){ p0[i]=tmp[i]; p1[i]=tmp[8+i]; }
  *(uint4*)dst = o0;
  *(uint4*)(dst+8) = o1;
}

// ---------------- Kernel C: LDS-K + direct-V swapped-QK MFMA ---------------
// Grid (8 heads, 64 pairs). Block 512 = 8 waves (vh = w>>2 in {0,1}: d-half;
// sq = w&3: 16-s slice of each 64-s unit). Two passes: q-tiles i and 127-i
// (16 rows each). K staged in LDS (dbuf, global_load_lds, XOR-swizzled),
// V^T read direct from global (L2-resident). P kept in registers (swapped
// QK^T); PV K=32 from paired units. Epilogue Osum unioned with K LDS.
__global__ __launch_bounds__(512, 4) void mlstm_mfma3(
    const ushort* __restrict__ qb, const ushort* __restrict__ kb,
    const ushort* __restrict__ vt,
    const float* __restrict__ csb, const float* __restrict__ Mxb,
    const float* __restrict__ mbb,
    const float* __restrict__ nw, float* __restrict__ out){
  const int h = blockIdx.x, ip = blockIdx.y;
  const int tid = threadIdx.x, l = tid & 63, w = tid >> 6;
  const int sq = w & 3, vh = w >> 2;
  const int g = l >> 4, m16 = l & 15;

  __shared__ __align__(16) float UNI[8704];     // max(K dbuf 32KB, Osum 34816B)
  __shared__ float rsL[4][16];
  ushort* Kb0 = (ushort*)UNI;
  ushort* Kb1 = Kb0 + 64*128;
  float*  Osum = UNI;                           // [(vh*4+sq)*16*68 + q*68 + d]

  const ushort* kbh = kb + h*DH;
  const ushort* vth = vt + (size_t)h*DH*S_LEN;
  const float*  mh  = mbb + h*S_LEN;
  const int hS = h*S_LEN;

  for (int pass=0; pass<2; ++pass){
    const int qt16 = pass ? (127 - ip) : ip;
    const int t0 = qt16*16;
    const int NU = (qt16>>2) + 1;
    const int tg = t0 + m16;
    const float Mq = Mxb[hS + tg];

    // Q B-frags: row n=m16 -> q=t0+m16, k-chunks by g
    bf16x8 qf0,qf1,qf2,qf3;
    { const ushort* qsrc = qb + (size_t)tg*E_DIM + h*DH + g*8;
      qf0 = *(const bf16x8*)(qsrc);
      qf1 = *(const bf16x8*)(qsrc+32);
      qf2 = *(const bf16x8*)(qsrc+64);
      qf3 = *(const bf16x8*)(qsrc+96); }

    f32x4 o0={0.f,0.f,0.f,0.f}, o1=o0, o2=o0, o3=o0;
    float rsq = 0.f;
    float pwA0=0.f, pwA1=0.f, pwA2=0.f, pwA3=0.f;

    // stage unit 0 -> buf0 (LDS union free: epilogue barrier passed)
    {
      const int L0 = w*128 + l;
      #pragma unroll
      for (int is=0; is<2; ++is){
        const int L = L0 + is*64;
        const int r = L>>4, c = L&15;
        stage16(kbh + (size_t)r*E_DIM + ((c ^ (r&7))<<3), Kb0 + L*8);
      }
    }

    for (int u=0; u<NU; ++u){
      __syncthreads();                       // stage(u) complete (vmcnt drained)
      if (u+1 < NU){
        ushort* dst = ((u+1)&1) ? Kb1 : Kb0;
        const int sk0n = (u+1)*64;
        const int L0 = w*128 + l;
        #pragma unroll
        for (int is=0; is<2; ++is){
          const int L = L0 + is*64;
          const int r = L>>4, c = L&15;
          stage16(kbh + (size_t)(sk0n + r)*E_DIM + ((c ^ (r&7))<<3), dst + L*8);
        }
      }
      // ---- QK^T from LDS buf[u&1] ----
      const ushort* kbuf = (u&1) ? Kb1 : Kb0;
      const int row = sq*16 + m16;
      const ushort* kbase = kbuf + row*128;
      const int rx = row & 7;
      bf16x8 ka0 = *(const bf16x8*)(kbase + ((0*4+g) ^ rx)*8);
      bf16x8 ka1 = *(const bf16x8*)(kbase + ((1*4+g) ^ rx)*8);
      bf16x8 ka2 = *(const bf16x8*)(kbase + ((2*4+g) ^ rx)*8);
      bf16x8 ka3 = *(const bf16x8*)(kbase + ((3*4+g) ^ rx)*8);
      f32x4 c0={0.f,0.f,0.f,0.f}, c1=c0;
      c0 = MFMA32(ka0, qf0, c0);
      c1 = MFMA32(ka1, qf1, c1);
      c0 = MFMA32(ka2, qf2, c0);
      c1 = MFMA32(ka3, qf3, c1);
      const int sgb = u*64 + sq*16 + g*4;
      const f32x4 m4 = *(const f32x4*)(mh + sgb);
      float pw0 = (sgb+0 <= tg) ? (c0[0]+c1[0])*__expf(m4[0]-Mq) : 0.f;
      float pw1 = (sgb+1 <= tg) ? (c0[1]+c1[1])*__expf(m4[1]-Mq) : 0.f;
      float pw2 = (sgb+2 <= tg) ? (c0[2]+c1[2])*__expf(m4[2]-Mq) : 0.f;
      float pw3 = (sgb+3 <= tg) ? (c0[3]+c1[3])*__expf(m4[3]-Mq) : 0.f;
      rsq += pw0+pw1+pw2+pw3;
      if (u & 1){
        // ---- PV pair (u-1, u), K=32 ----
        bf16x8 pa; unsigned* pau = (unsigned*)&pa;
        pau[0]=cvtpk(pwA0,pwA1); pau[1]=cvtpk(pwA2,pwA3);
        pau[2]=cvtpk(pw0,pw1);   pau[3]=cvtpk(pw2,pw3);
        const int sA = (u-1)*64 + sq*16 + g*4;
        const int sB = sA + 64;
        #pragma unroll
        for (int db=0; db<4; ++db){
          const int d = vh*64 + db*16 + m16;
          const ushort* vp = vth + (size_t)d*S_LEN;
          bf16x4 lo = *(const bf16x4*)(vp + sA);
          bf16x4 hi = *(const bf16x4*)(vp + sB);
          bf16x8 vb = __builtin_shufflevector(lo, hi, 0,1,2,3,4,5,6,7);
          if (db==0) o0 = MFMA32(pa, vb, o0);
          else if (db==1) o1 = MFMA32(pa, vb, o1);
          else if (db==2) o2 = MFMA32(pa, vb, o2);
          else o3 = MFMA32(pa, vb, o3);
        }
      } else {
        pwA0=pw0; pwA1=pw1; pwA2=pw2; pwA3=pw3;
      }
    }
    if (NU & 1){
      // tail: single unit NU-1, upper K-half zero (masked anyway)
      bf16x8 pa; unsigned* pau = (unsigned*)&pa;
      pau[0]=cvtpk(pwA0,pwA1); pau[1]=cvtpk(pwA2,pwA3);
      pau[2]=0u; pau[3]=0u;
      const int sA = (NU-1)*64 + sq*16 + g*4;
      #pragma unroll
      for (int db=0; db<4; ++db){
        const int d = vh*64 + db*16 + m16;
        const ushort* vp = vth + (size_t)d*S_LEN;
        bf16x4 lo = *(const bf16x4*)(vp + sA);
        bf16x8 vb = __builtin_shufflevector(lo, lo, 0,1,2,3,0,1,2,3);
        if (db==0) o0 = MFMA32(pa, vb, o0);
        else if (db==1) o1 = MFMA32(pa, vb, o1);
        else if (db==2) o2 = MFMA32(pa, vb, o2);
        else o3 = MFMA32(pa, vb, o3);
      }
    }

    // -------- epilogue --------
    __syncthreads();                 // all K LDS reads done; union -> Osum
    {
      float* ob = Osum + (size_t)(w*16)*68;
      #pragma unroll
      for (int r=0;r<4;++r){
        const int qrow = g*4+r;
        ob[qrow*68 + 0*16 + m16] = o0[r];
        ob[qrow*68 + 1*16 + m16] = o1[r];
        ob[qrow*68 + 2*16 + m16] = o2[r];
        ob[qrow*68 + 3*16 + m16] = o3[r];
      }
    }
    rsq += __shfl_xor(rsq, 16, 64);
    rsq += __shfl_xor(rsq, 32, 64);
    if (vh==0 && l < 16) rsL[sq][m16] = rsq;
    __syncthreads();

    {
      const int qr = tid >> 5;         // 0..15
      const int dc = tid & 31;         // 0..31
      const int d4 = dc*4;             // 0..124
      const int vhh = dc >> 4;
      const int dloc = d4 - vhh*64;
      f32x4 os = {0.f,0.f,0.f,0.f};
      #pragma unroll
      for (int s4=0;s4<4;++s4){
        const f32x4 part = *(const f32x4*)&Osum[(size_t)((vhh*4+s4)*16 + qr)*68 + dloc];
        os[0]+=part[0]; os[1]+=part[1]; os[2]+=part[2]; os[3]+=part[3];
      }
      const float rstot = rsL[0][qr]+rsL[1][qr]+rsL[2][qr]+rsL[3][qr];
      const int tq = t0 + qr;
      const float en = __expf(-(csb[hS+tq] + Mxb[hS+tq]));
      const float iv = 1.f/(fmaxf(fabsf(rstot), en) + 1e-6f);
      f32x4 hv;
      hv[0]=os[0]*iv; hv[1]=os[1]*iv; hv[2]=os[2]*iv; hv[3]=os[3]*iv;
      float s1 = hv[0]+hv[1]+hv[2]+hv[3];
      float s2 = hv[0]*hv[0]+hv[1]*hv[1]+hv[2]*hv[2]+hv[3]*hv[3];
      s1 += __shfl_xor(s1, 1, 64);  s2 += __shfl_xor(s2, 1, 64);
      s1 += __shfl_xor(s1, 2, 64);  s2 += __shfl_xor(s2, 2, 64);
      s1 += __shfl_xor(s1, 4, 64);  s2 += __shfl_xor(s2, 4, 64);
      s1 += __shfl_xor(s1, 8, 64);  s2 += __shfl_xor(s2, 8, 64);
      s1 += __shfl_xor(s1, 16, 64); s2 += __shfl_xor(s2, 16, 64);
      const float mean = s1 * (1.f/128.f);
      const float var  = s2 * (1.f/128.f) - mean*mean;
      const float rstd = rsqrtf(var + 1e-5f);
      const f32x4 nwv = *(const f32x4*)(nw + h*DH + d4);
      f32x4 ov;
      ov[0]=(hv[0]-mean)*rstd*nwv[0];
      ov[1]=(hv[1]-mean)*rstd*nwv[1];
      ov[2]=(hv[2]-mean)*rstd*nwv[2];
      ov[3]=(hv[3]-mean)*rstd*nwv[3];
      *(f32x4*)(out + (size_t)tq*E_DIM + h*DH + d4) = ov;
    }
    __syncthreads();                 // epilogue LDS reads done before next-pass staging
  }
}

extern "C" void kernel_launch(void* const* d_in, const int* in_sizes, int n_in,
                              void* d_out, int out_size, void* d_ws, size_t ws_size,
                              hipStream_t stream) {
  const float* q   = (const float*)d_in[0];
  const float* k   = (const float*)d_in[1];
  const float* v   = (const float*)d_in[2];
  const float* igw = (const float*)d_in[3];
  const float* igb = (const float*)d_in[4];
  const float* fgw = (const float*)d_in[5];
  const float* fgb = (const float*)d_in[6];
  const float* nw  = (const float*)d_in[7];
  float* outp = (float*)d_out;

  float* ws  = (float*)d_ws;
  float* ig  = ws;                 // NH*S
  float* lsf = ws + 1*NHEAD*S_LEN;
  float* csb = ws + 2*NHEAD*S_LEN;
  float* Mb  = ws + 3*NHEAD*S_LEN;
  float* mbf = ws + 4*NHEAD*S_LEN;
  ushort* qbb = (ushort*)(ws + 5*NHEAD*S_LEN);          // S*E bf16 (scaled)
  ushort* kbb = qbb + (size_t)S_LEN*E_DIM;              // S*E bf16
  ushort* vtb = kbb + (size_t)S_LEN*E_DIM;              // E*S bf16 (per-head V^T)

  gates_qk<<<512, 256, 0, stream>>>(q, k, v, igw, igb, fgw, fgb, ig, lsf, qbb, kbb);
  scan_kernel<<<NHEAD, 256, 0, stream>>>(ig, lsf, csb, Mb, mbf);
  vtrans<<<dim3(S_LEN/64, DH/64, NHEAD), 256, 0, stream>>>(v, vtb);
  mlstm_mfma3<<<dim3(NHEAD, 64), 512, 0, stream>>>(qbb, kbb, vtb, csb, Mb, mbf, nw, outp);
}